// Round 14
// baseline (143.352 us; speedup 1.0000x reference)
//
#include <hip/hip_runtime.h>
#include <cstdint>
#include <cstddef>

#define AS1 __attribute__((address_space(1)))
#define AS3 __attribute__((address_space(3)))

typedef __bf16 bf16x8 __attribute__((ext_vector_type(8)));
typedef __bf16 bf16x4 __attribute__((ext_vector_type(4)));
typedef float  f32x4  __attribute__((ext_vector_type(4)));
typedef float  f32x16 __attribute__((ext_vector_type(16)));
typedef unsigned int u32x4 __attribute__((ext_vector_type(4)));

#define MFMA_BF16(a, b, c) __builtin_amdgcn_mfma_f32_16x16x32_bf16((a), (b), (c), 0, 0, 0)
#define MFMA32(a, b, c)    __builtin_amdgcn_mfma_f32_32x32x16_bf16((a), (b), (c), 0, 0, 0)

// async global->LDS, 16B/lane. LDS base wave-uniform; HW adds lane*16. Global addr per-lane.
__device__ __forceinline__ void gload16(const __bf16* g, __bf16* l) {
  __builtin_amdgcn_global_load_lds((AS1 void*)(uintptr_t)g, (AS3 void*)l, 16, 0, 0);
}

__device__ __forceinline__ unsigned int cvtpk_bf16(float lo, float hi) {
  unsigned int r;
  asm("v_cvt_pk_bf16_f32 %0, %1, %2" : "=v"(r) : "v"(lo), "v"(hi));
  return r;
}

// v_permlane32_swap_b32 a, b : a[32:63] <-> b[0:31]
__device__ __forceinline__ void permswap(unsigned int& a, unsigned int& b) {
  asm volatile("v_permlane32_swap_b32 %0, %1" : "+v"(a), "+v"(b));
}

// raw v_exp_f32: computes 2^x
__device__ __forceinline__ float exp2_fast(float x) {
  float r;
  asm("v_exp_f32 %0, %1" : "=v"(r) : "v"(x));
  return r;
}

#define LOG2E 1.4426950408889634f

// ---------------- fp32 -> bf16 conversion (5 tensors) + mask-zero scan, one launch ----------------
__global__ void cvt_all_kernel(
    const float* __restrict__ hs, const float* __restrict__ qw, const float* __restrict__ kw,
    const float* __restrict__ vw, const float* __restrict__ ow,
    __bf16* __restrict__ Xb, __bf16* __restrict__ qwb, __bf16* __restrict__ kwb,
    __bf16* __restrict__ vwb, __bf16* __restrict__ owb,
    const unsigned long long* __restrict__ mask, int* __restrict__ flag)
{
  const int gid = blockIdx.x * blockDim.x + threadIdx.x;
  const int stride = gridDim.x * blockDim.x;
  for (int i = gid; i < 1179648; i += stride) {
    const float* s; __bf16* d; int o;
    if (i < 524288)       { s = hs; d = Xb;  o = i; }
    else if (i < 786432)  { s = qw; d = qwb; o = i - 524288; }
    else if (i < 917504)  { s = kw; d = kwb; o = i - 786432; }
    else if (i < 1048576) { s = vw; d = vwb; o = i - 917504; }
    else                  { s = ow; d = owb; o = i - 1048576; }
    const float4* p = (const float4*)(s + (size_t)o * 8);
    float4 a = p[0], b = p[1];
    bf16x8 v;
    v[0] = (__bf16)a.x; v[1] = (__bf16)a.y; v[2] = (__bf16)a.z; v[3] = (__bf16)a.w;
    v[4] = (__bf16)b.x; v[5] = (__bf16)b.y; v[6] = (__bf16)b.z; v[7] = (__bf16)b.w;
    *(bf16x8*)(d + (size_t)o * 8) = v;
  }
  bool nz = false;
  for (int i = gid; i < 2097152; i += stride) nz |= (mask[i] != 0ull);
  if (nz) atomicOr(flag, 1);
}

// ---------------- fused QGKV projection: 256x256 tile, BK=64, 8-phase counted-vmcnt pipeline ----------------
// (unchanged from round 12 — verified)
__global__ __launch_bounds__(512, 2) void proj_kernel(
    const __bf16* __restrict__ X,
    const __bf16* __restrict__ qw, const float* __restrict__ qb,
    const __bf16* __restrict__ kw, const float* __restrict__ kb,
    const __bf16* __restrict__ vw, const float* __restrict__ vb,
    __bf16* __restrict__ Qo, __bf16* __restrict__ Ko,
    __bf16* __restrict__ VTo, __bf16* __restrict__ Go)
{
  extern __shared__ char smem[];   // [0,64K): A bufs; [64K,128K): B bufs

  const int bid = blockIdx.x;      // 256 blocks, 1 per CU
  const int jj = bid >> 3;
  const int ntile = (bid & 7) * 2 + (jj >> 4);   // 2 ntiles per XCD -> B panels L2-hot
  const int mtile = jj & 15;
  const int m0 = mtile * 256, n0 = ntile * 256;

  const __bf16* W; const float* bias; int nb;
  if (n0 < 2048)      { W = qw; bias = qb; nb = n0; }
  else if (n0 < 3072) { W = kw; bias = kb; nb = n0 - 2048; }
  else                { W = vw; bias = vb; nb = n0 - 3072; }

  const int tid = threadIdx.x;
  const int wid = tid >> 6;        // 0..7
  const int wr = wid >> 2;         // 0..1 (M)
  const int wc = wid & 3;          // 0..3 (N)
  const int ln = tid & 63;
  const int qr = ln & 15, qg = ln >> 4;

  const int srow = ln >> 3;                    // 0..7
  const int sgran = ((ln & 7) ^ srow) * 8;     // source col element base

#define SA(buf, half, kt) do { \
  _Pragma("unroll") for (int i_ = 0; i_ < 2; ++i_) { \
    const int r0_ = (half) * 64 + i_ * 128 + wid * 8; \
    gload16(X + (size_t)(m0 + r0_ + srow) * 1024 + (kt) * 64 + sgran, \
            (__bf16*)(smem + (buf) * 32768 + r0_ * 128)); \
  } } while (0)

#define SB(buf, half, kt) do { \
  _Pragma("unroll") for (int i_ = 0; i_ < 2; ++i_) { \
    const int g_ = wid + i_ * 8; \
    const int r0_ = (g_ >> 2) * 64 + (half) * 32 + (g_ & 3) * 8; \
    gload16(W + (size_t)(nb + r0_ + srow) * 1024 + (kt) * 64 + sgran, \
            (__bf16*)(smem + 65536 + (buf) * 32768 + r0_ * 128)); \
  } } while (0)

#define LDA(buf, mh, mi, kk) (*(const bf16x8*)(smem + (buf) * 32768 + \
    (wr * 128 + (mh) * 64 + (mi) * 16 + qr) * 128 + (((kk) * 64 + qg * 16) ^ ((qr & 7) << 4))))
#define LDB(buf, nh, ni, kk) (*(const bf16x8*)(smem + 65536 + (buf) * 32768 + \
    (wc * 64 + (nh) * 32 + (ni) * 16 + qr) * 128 + (((kk) * 64 + qg * 16) ^ ((qr & 7) << 4))))

  f32x4 acc[8][4];
#pragma unroll
  for (int m = 0; m < 8; ++m)
#pragma unroll
    for (int n = 0; n < 4; ++n) acc[m][n] = 0.f;

  bf16x8 af[4][2], b0f[2][2], b1f[2][2];

#define QUAD(mh, nh, BF) do { \
  asm volatile("s_waitcnt lgkmcnt(0)"); \
  __builtin_amdgcn_sched_barrier(0); \
  __builtin_amdgcn_s_setprio(1); \
  _Pragma("unroll") for (int mi_ = 0; mi_ < 4; ++mi_) \
    _Pragma("unroll") for (int ni_ = 0; ni_ < 2; ++ni_) { \
      acc[(mh)*4+mi_][(nh)*2+ni_] = MFMA_BF16(af[mi_][0], BF[ni_][0], acc[(mh)*4+mi_][(nh)*2+ni_]); \
      acc[(mh)*4+mi_][(nh)*2+ni_] = MFMA_BF16(af[mi_][1], BF[ni_][1], acc[(mh)*4+mi_][(nh)*2+ni_]); \
    } \
  __builtin_amdgcn_s_setprio(0); \
} while (0)

#define BAR() __builtin_amdgcn_s_barrier()

  SA(0, 0, 0); SA(0, 1, 0); SB(0, 0, 0); SB(0, 1, 0);
  SA(1, 0, 1); SB(1, 0, 1); SB(1, 1, 1);
  asm volatile("s_waitcnt vmcnt(6)");
  BAR();

  for (int it = 0; it < 8; ++it) {
    const int tb = 2 * it + 1;
    const int tc = (2 * it + 2 < 16) ? 2 * it + 2 : 15;
    const int td = (2 * it + 3 < 16) ? 2 * it + 3 : 15;

    // ---- tile a (buf0) ----
#pragma unroll
    for (int mi = 0; mi < 4; ++mi) { af[mi][0] = LDA(0, 0, mi, 0); af[mi][1] = LDA(0, 0, mi, 1); }
#pragma unroll
    for (int ni = 0; ni < 2; ++ni) { b0f[ni][0] = LDB(0, 0, ni, 0); b0f[ni][1] = LDB(0, 0, ni, 1); }
    SA(1, 1, tb);
    BAR();
    QUAD(0, 0, b0f);
    BAR();
#pragma unroll
    for (int ni = 0; ni < 2; ++ni) { b1f[ni][0] = LDB(0, 1, ni, 0); b1f[ni][1] = LDB(0, 1, ni, 1); }
    SA(0, 0, tc);
    BAR();
    QUAD(0, 1, b1f);
    BAR();
#pragma unroll
    for (int mi = 0; mi < 4; ++mi) { af[mi][0] = LDA(0, 1, mi, 0); af[mi][1] = LDA(0, 1, mi, 1); }
    SB(0, 0, tc);
    BAR();
    QUAD(1, 1, b1f);
    BAR();
    SB(0, 1, tc);
    asm volatile("s_waitcnt vmcnt(6)");
    BAR();
    QUAD(1, 0, b0f);
    BAR();

    // ---- tile b (buf1) ----
#pragma unroll
    for (int mi = 0; mi < 4; ++mi) { af[mi][0] = LDA(1, 0, mi, 0); af[mi][1] = LDA(1, 0, mi, 1); }
#pragma unroll
    for (int ni = 0; ni < 2; ++ni) { b0f[ni][0] = LDB(1, 0, ni, 0); b0f[ni][1] = LDB(1, 0, ni, 1); }
    SA(0, 1, tc);
    BAR();
    QUAD(0, 0, b0f);
    BAR();
#pragma unroll
    for (int ni = 0; ni < 2; ++ni) { b1f[ni][0] = LDB(1, 1, ni, 0); b1f[ni][1] = LDB(1, 1, ni, 1); }
    SA(1, 0, td);
    BAR();
    QUAD(0, 1, b1f);
    BAR();
#pragma unroll
    for (int mi = 0; mi < 4; ++mi) { af[mi][0] = LDA(1, 1, mi, 0); af[mi][1] = LDA(1, 1, mi, 1); }
    SB(1, 0, td);
    BAR();
    QUAD(1, 1, b1f);
    BAR();
    SB(1, 1, td);
    asm volatile("s_waitcnt vmcnt(6)");
    BAR();
    QUAD(1, 0, b0f);
    BAR();
  }

  // epilogue: C/D layout col=lane&15, row=(lane>>4)*4+reg
#pragma unroll
  for (int mi = 0; mi < 8; ++mi) {
    const int gm0 = m0 + wr * 128 + mi * 16 + qg * 4;
    const int b = gm0 >> 11;
    const int s = gm0 & 2047;
#pragma unroll
    for (int ni = 0; ni < 4; ++ni) {
      const int nl = wc * 64 + ni * 16 + qr;
      const float bb = bias[nb + nl];
      if (n0 < 1024) {            // Q -> [b,h,s,d], pre-scaled by log2e/sqrt(d)
        const int col = n0 + nl, hh = col >> 6, dd = col & 63;
        __bf16* dst = Qo + ((size_t)((b << 4) + hh)) * 131072 + (size_t)s * 64 + dd;
#pragma unroll
        for (int rr = 0; rr < 4; ++rr) dst[(size_t)rr * 64] = (__bf16)((acc[mi][ni][rr] + bb) * (0.125f * LOG2E));
      } else if (n0 < 2048) {     // gate -> sigmoid -> [token, h*64+d]
        const int j = n0 - 1024 + nl;
        __bf16* dst = Go + (size_t)gm0 * 1024 + j;
#pragma unroll
        for (int rr = 0; rr < 4; ++rr) {
          const float v = acc[mi][ni][rr] + bb;
          dst[(size_t)rr * 1024] = (__bf16)(1.f / (1.f + __expf(-v)));
        }
      } else if (n0 < 3072) {     // K -> [b,h,s,d]
        const int j = n0 - 2048 + nl, hh = j >> 6, dd = j & 63;
        __bf16* dst = Ko + ((size_t)((b << 4) + hh)) * 131072 + (size_t)s * 64 + dd;
#pragma unroll
        for (int rr = 0; rr < 4; ++rr) dst[(size_t)rr * 64] = (__bf16)(acc[mi][ni][rr] + bb);
      } else {                    // V -> transposed [b,h,d,s]
        const int j = n0 - 3072 + nl, hh = j >> 6, dd = j & 63;
        bf16x4 pv;
#pragma unroll
        for (int rr = 0; rr < 4; ++rr) pv[rr] = (__bf16)(acc[mi][ni][rr] + bb);
        *(bf16x4*)(VTo + ((size_t)((b << 4) + hh)) * 131072 + (size_t)dd * 2048 + s) = pv;
      }
    }
  }
#undef SA
#undef SB
#undef LDA
#undef LDB
#undef QUAD
#undef BAR
}

// ---------------- flash attention: 3-buffer rotation, counted-vmcnt staging (T3/T4 applied) ----------------
// Block = 4 waves = one head, 128 q rows; wave w owns q0+w*32. Stage chunk c+2 while computing c;
// end-of-chunk waits vmcnt(4) (stage c+1 landed; c+2's 4 loads stay in flight) — never drains to 0
// in steady state. Merged softmax: one pass over p[32] per 64-kv chunk.
__global__ __launch_bounds__(256, 3) void attn_kernel(
    const __bf16* __restrict__ Qb, const __bf16* __restrict__ Kb,
    const __bf16* __restrict__ VT, const __bf16* __restrict__ G,
    const float* __restrict__ mask, const int* __restrict__ flag,
    __bf16* __restrict__ attn)
{
  __shared__ __bf16 Ksh[3][32][128];  // 3 x 8KB, swizzled
  __shared__ __bf16 Vsh[3][32][128];  // 48KB total -> 3 blocks/CU

  const int bid = blockIdx.x;    // 512 = 8 xcd * (4 heads * 16 qblocks)
  const int y = bid >> 3;        // 0..63
  const int hl = (bid & 7) * 4 + (y >> 4);  // 4 heads per XCD
  const int tid = threadIdx.x;
  const int w = tid >> 6;        // wave 0..3
  const int ln = tid & 63;
  const int lq = ln & 31;
  const int hi = ln >> 5;
  const int q0 = (y & 15) * 128 + w * 32;
  const int b = hl >> 4, h = hl & 15;

  const __bf16* Qh = Qb + (size_t)hl * 131072;
  const __bf16* Kh = Kb + (size_t)hl * 131072;
  const __bf16* Vh = VT + (size_t)hl * 131072;

  int kco[2], vco[2], ldst[2];
#pragma unroll
  for (int i = 0; i < 2; ++i) {
    const int prow = w * 8 + i * 4 + (ln >> 4);
    const int bphys = (ln & 15) * 16;
    const int blog = bphys ^ ((prow & 15) << 4);
    const int half = blog >> 7;
    const int col = (blog & 127) >> 1;
    kco[i] = (half * 32 + prow) * 64 + col;
    vco[i] = (half * 32 + prow) * 2048 + col;
    ldst[i] = (w * 8 + i * 4) * 256;
  }
  const int swz = (lq & 15) << 4;
  const int krow = lq * 256;

#define STAGE_AT(chunk, bb) do { \
  const int kv0_ = (chunk) * 64; \
  _Pragma("unroll") for (int i_ = 0; i_ < 2; ++i_) { \
    gload16(Kh + kv0_ * 64 + kco[i_], (__bf16*)((char*)&Ksh[bb][0][0] + ldst[i_])); \
    gload16(Vh + kv0_ + vco[i_],      (__bf16*)((char*)&Vsh[bb][0][0] + ldst[i_])); \
  } } while (0)

  bf16x8 qf[4];
#pragma unroll
  for (int ks = 0; ks < 4; ++ks)
    qf[ks] = *(const bf16x8*)(Qh + (size_t)(q0 + lq) * 64 + ks * 16 + hi * 8);

  f32x16 o0, o1;
#pragma unroll
  for (int i = 0; i < 16; ++i) { o0[i] = 0.f; o1[i] = 0.f; }
  float mrun = -1e30f, lrun = 0.f;

  const bool um = (*flag) != 0;

  // prologue: stage chunks 0 and 1; wait only for chunk 0 (chunk 1's 4 loads stay in flight)
  STAGE_AT(0, 0);
  STAGE_AT(1, 1);
  asm volatile("s_waitcnt vmcnt(4)" ::: "memory");
  __builtin_amdgcn_s_barrier();

  int bufc = 0;
  for (int c = 0; c < 32; ++c) {
    const int kv0 = c * 64;
    if (c < 30) {
      const int bnext = (bufc == 0) ? 2 : bufc - 1;  // (c+2)%3
      STAGE_AT(c + 2, bnext);
    }
    char* Kc = (char*)&Ksh[bufc][0][0];
    char* Vc = (char*)&Vsh[bufc][0][0];

    // QK^T, both 32-kv halves: 8 MFMAs back-to-back
    bf16x8 kfa[4], kfb[4];
#pragma unroll
    for (int ks = 0; ks < 4; ++ks) {
      kfa[ks] = *(const bf16x8*)(Kc + krow + ((ks * 32 + hi * 16) ^ swz));
      kfb[ks] = *(const bf16x8*)(Kc + krow + ((128 + ks * 32 + hi * 16) ^ swz));
    }
    f32x16 sa, sb;
#pragma unroll
    for (int i = 0; i < 16; ++i) { sa[i] = 0.f; sb[i] = 0.f; }
    __builtin_amdgcn_s_setprio(1);
#pragma unroll
    for (int ks = 0; ks < 4; ++ks) sa = MFMA32(kfa[ks], qf[ks], sa);
#pragma unroll
    for (int ks = 0; ks < 4; ++ks) sb = MFMA32(kfb[ks], qf[ks], sb);
    __builtin_amdgcn_s_setprio(0);

    float p[32];
    if (um) {
      const size_t mrow = (size_t)(q0 + lq) * 2048 + kv0;
#pragma unroll
      for (int i = 0; i < 16; ++i) {
        const int off = (i & 3) + 8 * (i >> 2) + 4 * hi;
        p[i]      = sa[i] + mask[mrow + off] * LOG2E;
        p[16 + i] = sb[i] + mask[mrow + 32 + off] * LOG2E;
      }
    } else {
#pragma unroll
      for (int i = 0; i < 16; ++i) { p[i] = sa[i]; p[16 + i] = sb[i]; }
    }

    // single row max over 64 kv: 31 local fmax + 1 cross-half shuffle
    float t = fmaxf(p[0], p[1]);
#pragma unroll
    for (int i = 2; i < 32; ++i) t = fmaxf(t, p[i]);
    t = fmaxf(t, __shfl_xor(t, 32));

    // defer-max: rescale only when running max grows by > 8 (rare; execz-skipped)
    if (t > mrun + 8.f) {
      const float al = exp2_fast(mrun - t);
      mrun = t;
      lrun *= al;
#pragma unroll
      for (int i = 0; i < 16; ++i) { o0[i] *= al; o1[i] *= al; }
    }

    float ps = 0.f;
#pragma unroll
    for (int i = 0; i < 32; ++i) { p[i] = exp2_fast(p[i] - mrun); ps += p[i]; }
    lrun += ps;   // per-lane partial; cross-half combine at end

    // pack P into B-frag layout: pa2[g], g = s32*2 + ks, from p[s32*16 + 8ks + ...]
    bf16x8 pa2[4];
#pragma unroll
    for (int g = 0; g < 4; ++g) {
      const int base = (g >> 1) * 16 + (g & 1) * 8;
      unsigned int c0 = cvtpk_bf16(p[base + 0], p[base + 1]);
      unsigned int c1 = cvtpk_bf16(p[base + 2], p[base + 3]);
      unsigned int c2 = cvtpk_bf16(p[base + 4], p[base + 5]);
      unsigned int c3 = cvtpk_bf16(p[base + 6], p[base + 7]);
      permswap(c0, c2);
      permswap(c1, c3);
      u32x4 wv; wv.x = c0; wv.y = c1; wv.z = c2; wv.w = c3;
      pa2[g] = __builtin_bit_cast(bf16x8, wv);
    }

    // PV: 8 MFMAs back-to-back
    __builtin_amdgcn_s_setprio(1);
#pragma unroll
    for (int g = 0; g < 4; ++g) {
      const int kvb = (g >> 1) * 64 + (g & 1) * 32 + hi * 16;
      bf16x8 v0 = *(const bf16x8*)(Vc + krow + ((0 + kvb) ^ swz));
      bf16x8 v1 = *(const bf16x8*)(Vc + krow + ((128 + kvb) ^ swz));
      o0 = MFMA32(v0, pa2[g], o0);
      o1 = MFMA32(v1, pa2[g], o1);
    }
    __builtin_amdgcn_s_setprio(0);

    // counted wait: stage(c+1) landed; stage(c+2)'s 4 loads stay in flight. Tail drains.
    if (c < 30) {
      asm volatile("s_waitcnt vmcnt(4)" ::: "memory");
    } else if (c == 30) {
      asm volatile("s_waitcnt vmcnt(0)" ::: "memory");
    }
    if (c < 31) __builtin_amdgcn_s_barrier();
    bufc = (bufc == 2) ? 0 : bufc + 1;
  }
#undef STAGE_AT

  // combine per-lane lrun across the kv-half pair, then normalize+gate+store
  lrun += __shfl_xor(lrun, 32);
  const float inv = 1.f / lrun;
  const size_t base = ((size_t)(b * 2048 + q0 + lq)) * 1024 + h * 64;
#pragma unroll
  for (int half = 0; half < 2; ++half) {
#pragma unroll
    for (int g = 0; g < 4; ++g) {
      const int d0 = half * 32 + g * 8 + hi * 4;
      bf16x4 g4 = *(const bf16x4*)(G + base + d0);
      bf16x4 r4;
#pragma unroll
      for (int j = 0; j < 4; ++j) {
        const float ov = half ? o1[g * 4 + j] : o0[g * 4 + j];
        r4[j] = (__bf16)(ov * inv * (float)g4[j]);
      }
      *(bf16x4*)(attn + base + d0) = r4;
    }
  }
}

// ---------------- O projection (bf16 in, fp32 out), 2-phase dbuf ----------------
__global__ __launch_bounds__(256) void oproj_kernel(
    const __bf16* __restrict__ A, const __bf16* __restrict__ ow,
    const float* __restrict__ ob, float* __restrict__ C)
{
  __shared__ __bf16 As[2][128][64];
  __shared__ __bf16 Bs[2][128][64];
  const int bid = blockIdx.x;
  const int ntile = bid & 7;
  const int mtile = bid >> 3;
  const int m0 = mtile * 128, n0 = ntile * 128;

  const int tid = threadIdx.x;
  const int wv = tid >> 6, ln = tid & 63;
  const int wr = wv >> 1, wc = wv & 1;
  const int qr = ln & 15, qg = ln >> 4;
  const int lrow = ln >> 3, lcol = (ln & 7) * 8;

  f32x4 acc[4][4];
#pragma unroll
  for (int m = 0; m < 4; ++m)
#pragma unroll
    for (int n = 0; n < 4; ++n) acc[m][n] = 0.f;

  __bf16 (*Asc)[64] = As[0], (*Asn)[64] = As[1];
  __bf16 (*Bsc)[64] = Bs[0], (*Bsn)[64] = Bs[1];

#pragma unroll
  for (int i = 0; i < 4; ++i) {
    const int rb = i * 32 + wv * 8;
    gload16(A  + (size_t)(m0 + rb + lrow) * 1024 + lcol, &Asc[rb][0]);
    gload16(ow + (size_t)(n0 + rb + lrow) * 1024 + lcol, &Bsc[rb][0]);
  }
  __syncthreads();

  for (int t = 0; t < 16; ++t) {
    if (t < 15) {
      const int k0 = (t + 1) * 64;
#pragma unroll
      for (int i = 0; i < 4; ++i) {
        const int rb = i * 32 + wv * 8;
        gload16(A  + (size_t)(m0 + rb + lrow) * 1024 + k0 + lcol, &Asn[rb][0]);
        gload16(ow + (size_t)(n0 + rb + lrow) * 1024 + k0 + lcol, &Bsn[rb][0]);
      }
    }
#pragma unroll
    for (int kk = 0; kk < 2; ++kk) {
      bf16x8 af[4], bfv[4];
#pragma unroll
      for (int m = 0; m < 4; ++m) af[m] = *(const bf16x8*)&Asc[wr * 64 + m * 16 + qr][kk * 32 + qg * 8];
#pragma unroll
      for (int n = 0; n < 4; ++n) bfv[n] = *(const bf16x8*)&Bsc[wc * 64 + n * 16 + qr][kk * 32 + qg * 8];
#pragma unroll
      for (int m = 0; m < 4; ++m)
#pragma unroll
        for (int n = 0; n < 4; ++n) acc[m][n] = MFMA_BF16(af[m], bfv[n], acc[m][n]);
    }
    __syncthreads();
    __bf16 (*ta)[64] = Asc; Asc = Asn; Asn = ta;
    __bf16 (*tb)[64] = Bsc; Bsc = Bsn; Bsn = tb;
  }

#pragma unroll
  for (int m = 0; m < 4; ++m) {
    const int gm0 = m0 + wr * 64 + m * 16 + qg * 4;
#pragma unroll
    for (int n = 0; n < 4; ++n) {
      const int gn = n0 + wc * 64 + n * 16 + qr;
      const float bb = ob[gn];
      float* dst = C + (size_t)gm0 * 1024 + gn;
#pragma unroll
      for (int rr = 0; rr < 4; ++rr) dst[(size_t)rr * 1024] = acc[m][n][rr] + bb;
    }
  }
}

extern "C" void kernel_launch(void* const* d_in, const int* in_sizes, int n_in,
                              void* d_out, int out_size, void* d_ws, size_t ws_size,
                              hipStream_t stream)
{
  const float* hs   = (const float*)d_in[0];
  const float* mask = (const float*)d_in[1];
  const float* qw   = (const float*)d_in[2];
  const float* qb   = (const float*)d_in[3];
  const float* kw   = (const float*)d_in[4];
  const float* kb   = (const float*)d_in[5];
  const float* vw   = (const float*)d_in[6];
  const float* vb   = (const float*)d_in[7];
  const float* ow   = (const float*)d_in[8];
  const float* ob   = (const float*)d_in[9];
  float* out = (float*)d_out;

  char* w = (char*)d_ws;
  int*    flag = (int*)w;
  __bf16* Xb  = (__bf16*)(w + 256);
  __bf16* qwb = Xb  + 4194304;
  __bf16* kwb = qwb + 2097152;
  __bf16* vwb = kwb + 1048576;
  __bf16* owb = vwb + 1048576;
  __bf16* Qo  = owb + 1048576;
  __bf16* Ko  = Qo  + 4194304;
  __bf16* VTo = Ko  + 4194304;
  __bf16* Go  = VTo + 4194304;
  __bf16* At  = Go  + 4194304;

  hipFuncSetAttribute((const void*)proj_kernel, hipFuncAttributeMaxDynamicSharedMemorySize, 131072);

  hipMemsetAsync(flag, 0, sizeof(int), stream);
  cvt_all_kernel<<<2048, 256, 0, stream>>>(hs, qw, kw, vw, ow, Xb, qwb, kwb, vwb, owb,
                                           (const unsigned long long*)mask, flag);
  proj_kernel<<<256, 512, 131072, stream>>>(Xb, qwb, qb, kwb, kb, vwb, vb, Qo, Ko, VTo, Go);
  attn_kernel<<<512, 256, 0, stream>>>(Qo, Ko, VTo, Go, mask, flag, At);
  oproj_kernel<<<256, 256, 0, stream>>>(At, owb, ob, out);
}

// Round 15
// 137.920 us; speedup vs baseline: 1.0394x; 1.0394x over previous
//
#include <hip/hip_runtime.h>
#include <cstdint>
#include <cstddef>

#define AS1 __attribute__((address_space(1)))
#define AS3 __attribute__((address_space(3)))

typedef __bf16 bf16x8 __attribute__((ext_vector_type(8)));
typedef __bf16 bf16x4 __attribute__((ext_vector_type(4)));
typedef float  f32x4  __attribute__((ext_vector_type(4)));
typedef float  f32x16 __attribute__((ext_vector_type(16)));
typedef unsigned int u32x4 __attribute__((ext_vector_type(4)));

#define MFMA_BF16(a, b, c) __builtin_amdgcn_mfma_f32_16x16x32_bf16((a), (b), (c), 0, 0, 0)
#define MFMA32(a, b, c)    __builtin_amdgcn_mfma_f32_32x32x16_bf16((a), (b), (c), 0, 0, 0)

// async global->LDS, 16B/lane. LDS base wave-uniform; HW adds lane*16. Global addr per-lane.
__device__ __forceinline__ void gload16(const __bf16* g, __bf16* l) {
  __builtin_amdgcn_global_load_lds((AS1 void*)(uintptr_t)g, (AS3 void*)l, 16, 0, 0);
}

__device__ __forceinline__ unsigned int cvtpk_bf16(float lo, float hi) {
  unsigned int r;
  asm("v_cvt_pk_bf16_f32 %0, %1, %2" : "=v"(r) : "v"(lo), "v"(hi));
  return r;
}

// v_permlane32_swap_b32 a, b : a[32:63] <-> b[0:31]
__device__ __forceinline__ void permswap(unsigned int& a, unsigned int& b) {
  asm volatile("v_permlane32_swap_b32 %0, %1" : "+v"(a), "+v"(b));
}

// raw v_exp_f32: computes 2^x
__device__ __forceinline__ float exp2_fast(float x) {
  float r;
  asm("v_exp_f32 %0, %1" : "=v"(r) : "v"(x));
  return r;
}

#define LOG2E 1.4426950408889634f

// ---------------- fp32 -> bf16 conversion (5 tensors) + mask-zero scan, one launch ----------------
__global__ void cvt_all_kernel(
    const float* __restrict__ hs, const float* __restrict__ qw, const float* __restrict__ kw,
    const float* __restrict__ vw, const float* __restrict__ ow,
    __bf16* __restrict__ Xb, __bf16* __restrict__ qwb, __bf16* __restrict__ kwb,
    __bf16* __restrict__ vwb, __bf16* __restrict__ owb,
    const unsigned long long* __restrict__ mask, int* __restrict__ flag)
{
  const int gid = blockIdx.x * blockDim.x + threadIdx.x;
  const int stride = gridDim.x * blockDim.x;
  for (int i = gid; i < 1179648; i += stride) {
    const float* s; __bf16* d; int o;
    if (i < 524288)       { s = hs; d = Xb;  o = i; }
    else if (i < 786432)  { s = qw; d = qwb; o = i - 524288; }
    else if (i < 917504)  { s = kw; d = kwb; o = i - 786432; }
    else if (i < 1048576) { s = vw; d = vwb; o = i - 917504; }
    else                  { s = ow; d = owb; o = i - 1048576; }
    const float4* p = (const float4*)(s + (size_t)o * 8);
    float4 a = p[0], b = p[1];
    bf16x8 v;
    v[0] = (__bf16)a.x; v[1] = (__bf16)a.y; v[2] = (__bf16)a.z; v[3] = (__bf16)a.w;
    v[4] = (__bf16)b.x; v[5] = (__bf16)b.y; v[6] = (__bf16)b.z; v[7] = (__bf16)b.w;
    *(bf16x8*)(d + (size_t)o * 8) = v;
  }
  bool nz = false;
  for (int i = gid; i < 2097152; i += stride) nz |= (mask[i] != 0ull);
  if (nz) atomicOr(flag, 1);
}

// ---------------- fused QGKV projection: 256x256 tile, BK=64, 8-phase counted-vmcnt pipeline ----------------
// (unchanged from round 12 — verified)
__global__ __launch_bounds__(512, 2) void proj_kernel(
    const __bf16* __restrict__ X,
    const __bf16* __restrict__ qw, const float* __restrict__ qb,
    const __bf16* __restrict__ kw, const float* __restrict__ kb,
    const __bf16* __restrict__ vw, const float* __restrict__ vb,
    __bf16* __restrict__ Qo, __bf16* __restrict__ Ko,
    __bf16* __restrict__ VTo, __bf16* __restrict__ Go)
{
  extern __shared__ char smem[];   // [0,64K): A bufs; [64K,128K): B bufs

  const int bid = blockIdx.x;      // 256 blocks, 1 per CU
  const int jj = bid >> 3;
  const int ntile = (bid & 7) * 2 + (jj >> 4);   // 2 ntiles per XCD -> B panels L2-hot
  const int mtile = jj & 15;
  const int m0 = mtile * 256, n0 = ntile * 256;

  const __bf16* W; const float* bias; int nb;
  if (n0 < 2048)      { W = qw; bias = qb; nb = n0; }
  else if (n0 < 3072) { W = kw; bias = kb; nb = n0 - 2048; }
  else                { W = vw; bias = vb; nb = n0 - 3072; }

  const int tid = threadIdx.x;
  const int wid = tid >> 6;        // 0..7
  const int wr = wid >> 2;         // 0..1 (M)
  const int wc = wid & 3;          // 0..3 (N)
  const int ln = tid & 63;
  const int qr = ln & 15, qg = ln >> 4;

  const int srow = ln >> 3;                    // 0..7
  const int sgran = ((ln & 7) ^ srow) * 8;     // source col element base

#define SA(buf, half, kt) do { \
  _Pragma("unroll") for (int i_ = 0; i_ < 2; ++i_) { \
    const int r0_ = (half) * 64 + i_ * 128 + wid * 8; \
    gload16(X + (size_t)(m0 + r0_ + srow) * 1024 + (kt) * 64 + sgran, \
            (__bf16*)(smem + (buf) * 32768 + r0_ * 128)); \
  } } while (0)

#define SB(buf, half, kt) do { \
  _Pragma("unroll") for (int i_ = 0; i_ < 2; ++i_) { \
    const int g_ = wid + i_ * 8; \
    const int r0_ = (g_ >> 2) * 64 + (half) * 32 + (g_ & 3) * 8; \
    gload16(W + (size_t)(nb + r0_ + srow) * 1024 + (kt) * 64 + sgran, \
            (__bf16*)(smem + 65536 + (buf) * 32768 + r0_ * 128)); \
  } } while (0)

#define LDA(buf, mh, mi, kk) (*(const bf16x8*)(smem + (buf) * 32768 + \
    (wr * 128 + (mh) * 64 + (mi) * 16 + qr) * 128 + (((kk) * 64 + qg * 16) ^ ((qr & 7) << 4))))
#define LDB(buf, nh, ni, kk) (*(const bf16x8*)(smem + 65536 + (buf) * 32768 + \
    (wc * 64 + (nh) * 32 + (ni) * 16 + qr) * 128 + (((kk) * 64 + qg * 16) ^ ((qr & 7) << 4))))

  f32x4 acc[8][4];
#pragma unroll
  for (int m = 0; m < 8; ++m)
#pragma unroll
    for (int n = 0; n < 4; ++n) acc[m][n] = 0.f;

  bf16x8 af[4][2], b0f[2][2], b1f[2][2];

#define QUAD(mh, nh, BF) do { \
  asm volatile("s_waitcnt lgkmcnt(0)"); \
  __builtin_amdgcn_sched_barrier(0); \
  __builtin_amdgcn_s_setprio(1); \
  _Pragma("unroll") for (int mi_ = 0; mi_ < 4; ++mi_) \
    _Pragma("unroll") for (int ni_ = 0; ni_ < 2; ++ni_) { \
      acc[(mh)*4+mi_][(nh)*2+ni_] = MFMA_BF16(af[mi_][0], BF[ni_][0], acc[(mh)*4+mi_][(nh)*2+ni_]); \
      acc[(mh)*4+mi_][(nh)*2+ni_] = MFMA_BF16(af[mi_][1], BF[ni_][1], acc[(mh)*4+mi_][(nh)*2+ni_]); \
    } \
  __builtin_amdgcn_s_setprio(0); \
} while (0)

#define BAR() __builtin_amdgcn_s_barrier()

  SA(0, 0, 0); SA(0, 1, 0); SB(0, 0, 0); SB(0, 1, 0);
  SA(1, 0, 1); SB(1, 0, 1); SB(1, 1, 1);
  asm volatile("s_waitcnt vmcnt(6)");
  BAR();

  for (int it = 0; it < 8; ++it) {
    const int tb = 2 * it + 1;
    const int tc = (2 * it + 2 < 16) ? 2 * it + 2 : 15;
    const int td = (2 * it + 3 < 16) ? 2 * it + 3 : 15;

    // ---- tile a (buf0) ----
#pragma unroll
    for (int mi = 0; mi < 4; ++mi) { af[mi][0] = LDA(0, 0, mi, 0); af[mi][1] = LDA(0, 0, mi, 1); }
#pragma unroll
    for (int ni = 0; ni < 2; ++ni) { b0f[ni][0] = LDB(0, 0, ni, 0); b0f[ni][1] = LDB(0, 0, ni, 1); }
    SA(1, 1, tb);
    BAR();
    QUAD(0, 0, b0f);
    BAR();
#pragma unroll
    for (int ni = 0; ni < 2; ++ni) { b1f[ni][0] = LDB(0, 1, ni, 0); b1f[ni][1] = LDB(0, 1, ni, 1); }
    SA(0, 0, tc);
    BAR();
    QUAD(0, 1, b1f);
    BAR();
#pragma unroll
    for (int mi = 0; mi < 4; ++mi) { af[mi][0] = LDA(0, 1, mi, 0); af[mi][1] = LDA(0, 1, mi, 1); }
    SB(0, 0, tc);
    BAR();
    QUAD(1, 1, b1f);
    BAR();
    SB(0, 1, tc);
    asm volatile("s_waitcnt vmcnt(6)");
    BAR();
    QUAD(1, 0, b0f);
    BAR();

    // ---- tile b (buf1) ----
#pragma unroll
    for (int mi = 0; mi < 4; ++mi) { af[mi][0] = LDA(1, 0, mi, 0); af[mi][1] = LDA(1, 0, mi, 1); }
#pragma unroll
    for (int ni = 0; ni < 2; ++ni) { b0f[ni][0] = LDB(1, 0, ni, 0); b0f[ni][1] = LDB(1, 0, ni, 1); }
    SA(0, 1, tc);
    BAR();
    QUAD(0, 0, b0f);
    BAR();
#pragma unroll
    for (int ni = 0; ni < 2; ++ni) { b1f[ni][0] = LDB(1, 1, ni, 0); b1f[ni][1] = LDB(1, 1, ni, 1); }
    SA(1, 0, td);
    BAR();
    QUAD(0, 1, b1f);
    BAR();
#pragma unroll
    for (int mi = 0; mi < 4; ++mi) { af[mi][0] = LDA(1, 1, mi, 0); af[mi][1] = LDA(1, 1, mi, 1); }
    SB(1, 0, td);
    BAR();
    QUAD(1, 1, b1f);
    BAR();
    SB(1, 1, td);
    asm volatile("s_waitcnt vmcnt(6)");
    BAR();
    QUAD(1, 0, b0f);
    BAR();
  }

  // epilogue: C/D layout col=lane&15, row=(lane>>4)*4+reg
#pragma unroll
  for (int mi = 0; mi < 8; ++mi) {
    const int gm0 = m0 + wr * 128 + mi * 16 + qg * 4;
    const int b = gm0 >> 11;
    const int s = gm0 & 2047;
#pragma unroll
    for (int ni = 0; ni < 4; ++ni) {
      const int nl = wc * 64 + ni * 16 + qr;
      const float bb = bias[nb + nl];
      if (n0 < 1024) {            // Q -> [b,h,s,d], pre-scaled by log2e/sqrt(d)
        const int col = n0 + nl, hh = col >> 6, dd = col & 63;
        __bf16* dst = Qo + ((size_t)((b << 4) + hh)) * 131072 + (size_t)s * 64 + dd;
#pragma unroll
        for (int rr = 0; rr < 4; ++rr) dst[(size_t)rr * 64] = (__bf16)((acc[mi][ni][rr] + bb) * (0.125f * LOG2E));
      } else if (n0 < 2048) {     // gate -> sigmoid -> [token, h*64+d]
        const int j = n0 - 1024 + nl;
        __bf16* dst = Go + (size_t)gm0 * 1024 + j;
#pragma unroll
        for (int rr = 0; rr < 4; ++rr) {
          const float v = acc[mi][ni][rr] + bb;
          dst[(size_t)rr * 1024] = (__bf16)(1.f / (1.f + __expf(-v)));
        }
      } else if (n0 < 3072) {     // K -> [b,h,s,d]
        const int j = n0 - 2048 + nl, hh = j >> 6, dd = j & 63;
        __bf16* dst = Ko + ((size_t)((b << 4) + hh)) * 131072 + (size_t)s * 64 + dd;
#pragma unroll
        for (int rr = 0; rr < 4; ++rr) dst[(size_t)rr * 64] = (__bf16)(acc[mi][ni][rr] + bb);
      } else {                    // V -> transposed [b,h,d,s]
        const int j = n0 - 3072 + nl, hh = j >> 6, dd = j & 63;
        bf16x4 pv;
#pragma unroll
        for (int rr = 0; rr < 4; ++rr) pv[rr] = (__bf16)(acc[mi][ni][rr] + bb);
        *(bf16x4*)(VTo + ((size_t)((b << 4) + hh)) * 131072 + (size_t)dd * 2048 + s) = pv;
      }
    }
  }
#undef SA
#undef SB
#undef LDA
#undef LDB
#undef QUAD
#undef BAR
}

// ---------------- flash attention: chunk-pair unroll, dbuf LDS K/V, swapped-QK^T ----------------
// Block = 4 waves = one head, 128 q rows; wave w owns q0+w*32. Buffers hold a PAIR of 64-kv
// chunks; stage pair t+1 while computing pair t. Between barriers the stream is
// QK(c0);QK(c1);SM(c0);PV(c0);SM(c1);PV(c1) — independent chains the scheduler interleaves
// (QK(c1) MFMA hides under SM(c0) VALU; PV(c0) hides under SM(c1)). Barriers: 16 (was 32).
__global__ __launch_bounds__(256, 2) void attn_kernel(
    const __bf16* __restrict__ Qb, const __bf16* __restrict__ Kb,
    const __bf16* __restrict__ VT, const __bf16* __restrict__ G,
    const float* __restrict__ mask, const int* __restrict__ flag,
    __bf16* __restrict__ attn)
{
  __shared__ __bf16 Ksh[2][2][32][128];  // [buf][sub][prow][256B] = 32KB
  __shared__ __bf16 Vsh[2][2][32][128];  // 32KB -> 64KB total, 2 blocks/CU

  const int bid = blockIdx.x;    // 512 = 8 xcd * (4 heads * 16 qblocks)
  const int y = bid >> 3;        // 0..63
  const int hl = (bid & 7) * 4 + (y >> 4);  // 4 heads per XCD
  const int tid = threadIdx.x;
  const int w = tid >> 6;        // wave 0..3
  const int ln = tid & 63;
  const int lq = ln & 31;
  const int hi = ln >> 5;
  const int q0 = (y & 15) * 128 + w * 32;
  const int b = hl >> 4, h = hl & 15;

  const __bf16* Qh = Qb + (size_t)hl * 131072;
  const __bf16* Kh = Kb + (size_t)hl * 131072;
  const __bf16* Vh = VT + (size_t)hl * 131072;

  // staging source offsets (elements within head), chunk-invariant parts
  int kco[2], vco[2], ldst[2];
#pragma unroll
  for (int i = 0; i < 2; ++i) {
    const int prow = w * 8 + i * 4 + (ln >> 4);  // physical LDS row 0..31
    const int bphys = (ln & 15) * 16;
    const int blog = bphys ^ ((prow & 15) << 4);
    const int half = blog >> 7;             // K: kv-half | V: d-half
    const int col = (blog & 127) >> 1;      // K: d | V: kv-local
    kco[i] = (half * 32 + prow) * 64 + col;
    vco[i] = (half * 32 + prow) * 2048 + col;
    ldst[i] = (w * 8 + i * 4) * 256;        // byte offset within an 8KB sub-chunk block
  }
  const int swz = (lq & 15) << 4;
  const int krow = lq * 256;

  char* const KB = (char*)&Ksh[0][0][0][0];
  char* const VB = (char*)&Vsh[0][0][0][0];

  // stage one 64-kv chunk into sub-block sb of buffer bb
#define STAGE_SUB(chunk, bb, sb) do { \
  const int kv0_ = (chunk) * 64; \
  char* kd_ = KB + ((bb) * 2 + (sb)) * 8192; \
  char* vd_ = VB + ((bb) * 2 + (sb)) * 8192; \
  _Pragma("unroll") for (int i_ = 0; i_ < 2; ++i_) { \
    gload16(Kh + kv0_ * 64 + kco[i_], (__bf16*)(kd_ + ldst[i_])); \
    gload16(Vh + kv0_ + vco[i_],      (__bf16*)(vd_ + ldst[i_])); \
  } } while (0)

  bf16x8 qf[4];
#pragma unroll
  for (int ks = 0; ks < 4; ++ks)
    qf[ks] = *(const bf16x8*)(Qh + (size_t)(q0 + lq) * 64 + ks * 16 + hi * 8);

  f32x16 o0, o1;
#pragma unroll
  for (int i = 0; i < 16; ++i) { o0[i] = 0.f; o1[i] = 0.f; }
  float mrun = -1e30f, lrun = 0.f;

  const bool um = (*flag) != 0;

  // prologue: stage pair 0
  STAGE_SUB(0, 0, 0);
  STAGE_SUB(1, 0, 1);
  __syncthreads();

  int buf = 0;
  for (int t = 0; t < 16; ++t) {
    if (t < 15) {
      STAGE_SUB(2 * t + 2, buf ^ 1, 0);
      STAGE_SUB(2 * t + 3, buf ^ 1, 1);
    }

    // ---- QK for both sub-chunks (32 MFMAs total, independent) ----
    f32x16 s0a, s0b, s1a, s1b;
#pragma unroll
    for (int i = 0; i < 16; ++i) { s0a[i] = 0.f; s0b[i] = 0.f; s1a[i] = 0.f; s1b[i] = 0.f; }
    {
      char* Kc0 = KB + (buf * 2 + 0) * 8192;
      char* Kc1 = KB + (buf * 2 + 1) * 8192;
      bf16x8 kfa[4], kfb[4];
#pragma unroll
      for (int ks = 0; ks < 4; ++ks) {
        kfa[ks] = *(const bf16x8*)(Kc0 + krow + ((ks * 32 + hi * 16) ^ swz));
        kfb[ks] = *(const bf16x8*)(Kc0 + krow + ((128 + ks * 32 + hi * 16) ^ swz));
      }
      __builtin_amdgcn_s_setprio(1);
#pragma unroll
      for (int ks = 0; ks < 4; ++ks) s0a = MFMA32(kfa[ks], qf[ks], s0a);
#pragma unroll
      for (int ks = 0; ks < 4; ++ks) s0b = MFMA32(kfb[ks], qf[ks], s0b);
      __builtin_amdgcn_s_setprio(0);
#pragma unroll
      for (int ks = 0; ks < 4; ++ks) {
        kfa[ks] = *(const bf16x8*)(Kc1 + krow + ((ks * 32 + hi * 16) ^ swz));
        kfb[ks] = *(const bf16x8*)(Kc1 + krow + ((128 + ks * 32 + hi * 16) ^ swz));
      }
      __builtin_amdgcn_s_setprio(1);
#pragma unroll
      for (int ks = 0; ks < 4; ++ks) s1a = MFMA32(kfa[ks], qf[ks], s1a);
#pragma unroll
      for (int ks = 0; ks < 4; ++ks) s1b = MFMA32(kfb[ks], qf[ks], s1b);
      __builtin_amdgcn_s_setprio(0);
    }

    // ---- SM + PV per sub-chunk (serial online-softmax order; chains interleave) ----
#pragma unroll
    for (int sub = 0; sub < 2; ++sub) {
      const int kv0 = (2 * t + sub) * 64;
      char* Vc = VB + (buf * 2 + sub) * 8192;
      f32x16& sA = sub ? s1a : s0a;
      f32x16& sB = sub ? s1b : s0b;

      float p[32];
      if (um) {
        const size_t mrow = (size_t)(q0 + lq) * 2048 + kv0;
#pragma unroll
        for (int i = 0; i < 16; ++i) {
          const int off = (i & 3) + 8 * (i >> 2) + 4 * hi;
          p[i]      = sA[i] + mask[mrow + off] * LOG2E;
          p[16 + i] = sB[i] + mask[mrow + 32 + off] * LOG2E;
        }
      } else {
#pragma unroll
        for (int i = 0; i < 16; ++i) { p[i] = sA[i]; p[16 + i] = sB[i]; }
      }

      float tmx = fmaxf(p[0], p[1]);
#pragma unroll
      for (int i = 2; i < 32; ++i) tmx = fmaxf(tmx, p[i]);
      tmx = fmaxf(tmx, __shfl_xor(tmx, 32));

      if (tmx > mrun + 8.f) {
        const float al = exp2_fast(mrun - tmx);
        mrun = tmx;
        lrun *= al;
#pragma unroll
        for (int i = 0; i < 16; ++i) { o0[i] *= al; o1[i] *= al; }
      }

      float ps = 0.f;
#pragma unroll
      for (int i = 0; i < 32; ++i) { p[i] = exp2_fast(p[i] - mrun); ps += p[i]; }
      lrun += ps;

      bf16x8 pa2[4];
#pragma unroll
      for (int g = 0; g < 4; ++g) {
        const int base = (g >> 1) * 16 + (g & 1) * 8;
        unsigned int c0 = cvtpk_bf16(p[base + 0], p[base + 1]);
        unsigned int c1 = cvtpk_bf16(p[base + 2], p[base + 3]);
        unsigned int c2 = cvtpk_bf16(p[base + 4], p[base + 5]);
        unsigned int c3 = cvtpk_bf16(p[base + 6], p[base + 7]);
        permswap(c0, c2);
        permswap(c1, c3);
        u32x4 wv; wv.x = c0; wv.y = c1; wv.z = c2; wv.w = c3;
        pa2[g] = __builtin_bit_cast(bf16x8, wv);
      }

      __builtin_amdgcn_s_setprio(1);
#pragma unroll
      for (int g = 0; g < 4; ++g) {
        const int kvb = (g >> 1) * 64 + (g & 1) * 32 + hi * 16;
        bf16x8 v0 = *(const bf16x8*)(Vc + krow + ((0 + kvb) ^ swz));
        bf16x8 v1 = *(const bf16x8*)(Vc + krow + ((128 + kvb) ^ swz));
        o0 = MFMA32(v0, pa2[g], o0);
        o1 = MFMA32(v1, pa2[g], o1);
      }
      __builtin_amdgcn_s_setprio(0);
    }

    __syncthreads();   // drains vmcnt (next pair staged) + orders LDS reuse
    buf ^= 1;
  }
#undef STAGE_SUB

  // combine per-lane lrun across the kv-half pair, then normalize+gate+store
  lrun += __shfl_xor(lrun, 32);
  const float inv = 1.f / lrun;
  const size_t base = ((size_t)(b * 2048 + q0 + lq)) * 1024 + h * 64;
#pragma unroll
  for (int half = 0; half < 2; ++half) {
#pragma unroll
    for (int g = 0; g < 4; ++g) {
      const int d0 = half * 32 + g * 8 + hi * 4;
      bf16x4 g4 = *(const bf16x4*)(G + base + d0);
      bf16x4 r4;
#pragma unroll
      for (int j = 0; j < 4; ++j) {
        const float ov = half ? o1[g * 4 + j] : o0[g * 4 + j];
        r4[j] = (__bf16)(ov * inv * (float)g4[j]);
      }
      *(bf16x4*)(attn + base + d0) = r4;
    }
  }
}

// ---------------- O projection (bf16 in, fp32 out), 2-phase dbuf ----------------
__global__ __launch_bounds__(256) void oproj_kernel(
    const __bf16* __restrict__ A, const __bf16* __restrict__ ow,
    const float* __restrict__ ob, float* __restrict__ C)
{
  __shared__ __bf16 As[2][128][64];
  __shared__ __bf16 Bs[2][128][64];
  const int bid = blockIdx.x;
  const int ntile = bid & 7;
  const int mtile = bid >> 3;
  const int m0 = mtile * 128, n0 = ntile * 128;

  const int tid = threadIdx.x;
  const int wv = tid >> 6, ln = tid & 63;
  const int wr = wv >> 1, wc = wv & 1;
  const int qr = ln & 15, qg = ln >> 4;
  const int lrow = ln >> 3, lcol = (ln & 7) * 8;

  f32x4 acc[4][4];
#pragma unroll
  for (int m = 0; m < 4; ++m)
#pragma unroll
    for (int n = 0; n < 4; ++n) acc[m][n] = 0.f;

  __bf16 (*Asc)[64] = As[0], (*Asn)[64] = As[1];
  __bf16 (*Bsc)[64] = Bs[0], (*Bsn)[64] = Bs[1];

#pragma unroll
  for (int i = 0; i < 4; ++i) {
    const int rb = i * 32 + wv * 8;
    gload16(A  + (size_t)(m0 + rb + lrow) * 1024 + lcol, &Asc[rb][0]);
    gload16(ow + (size_t)(n0 + rb + lrow) * 1024 + lcol, &Bsc[rb][0]);
  }
  __syncthreads();

  for (int t = 0; t < 16; ++t) {
    if (t < 15) {
      const int k0 = (t + 1) * 64;
#pragma unroll
      for (int i = 0; i < 4; ++i) {
        const int rb = i * 32 + wv * 8;
        gload16(A  + (size_t)(m0 + rb + lrow) * 1024 + k0 + lcol, &Asn[rb][0]);
        gload16(ow + (size_t)(n0 + rb + lrow) * 1024 + k0 + lcol, &Bsn[rb][0]);
      }
    }
#pragma unroll
    for (int kk = 0; kk < 2; ++kk) {
      bf16x8 af[4], bfv[4];
#pragma unroll
      for (int m = 0; m < 4; ++m) af[m] = *(const bf16x8*)&Asc[wr * 64 + m * 16 + qr][kk * 32 + qg * 8];
#pragma unroll
      for (int n = 0; n < 4; ++n) bfv[n] = *(const bf16x8*)&Bsc[wc * 64 + n * 16 + qr][kk * 32 + qg * 8];
#pragma unroll
      for (int m = 0; m < 4; ++m)
#pragma unroll
        for (int n = 0; n < 4; ++n) acc[m][n] = MFMA_BF16(af[m], bfv[n], acc[m][n]);
    }
    __syncthreads();
    __bf16 (*ta)[64] = Asc; Asc = Asn; Asn = ta;
    __bf16 (*tb)[64] = Bsc; Bsc = Bsn; Bsn = tb;
  }

#pragma unroll
  for (int m = 0; m < 4; ++m) {
    const int gm0 = m0 + wr * 64 + m * 16 + qg * 4;
#pragma unroll
    for (int n = 0; n < 4; ++n) {
      const int gn = n0 + wc * 64 + n * 16 + qr;
      const float bb = ob[gn];
      float* dst = C + (size_t)gm0 * 1024 + gn;
#pragma unroll
      for (int rr = 0; rr < 4; ++rr) dst[(size_t)rr * 1024] = acc[m][n][rr] + bb;
    }
  }
}

extern "C" void kernel_launch(void* const* d_in, const int* in_sizes, int n_in,
                              void* d_out, int out_size, void* d_ws, size_t ws_size,
                              hipStream_t stream)
{
  const float* hs   = (const float*)d_in[0];
  const float* mask = (const float*)d_in[1];
  const float* qw   = (const float*)d_in[2];
  const float* qb   = (const float*)d_in[3];
  const float* kw   = (const float*)d_in[4];
  const float* kb   = (const float*)d_in[5];
  const float* vw   = (const float*)d_in[6];
  const float* vb   = (const float*)d_in[7];
  const float* ow   = (const float*)d_in[8];
  const float* ob   = (const float*)d_in[9];
  float* out = (float*)d_out;

  char* w = (char*)d_ws;
  int*    flag = (int*)w;
  __bf16* Xb  = (__bf16*)(w + 256);
  __bf16* qwb = Xb  + 4194304;
  __bf16* kwb = qwb + 2097152;
  __bf16* vwb = kwb + 1048576;
  __bf16* owb = vwb + 1048576;
  __bf16* Qo  = owb + 1048576;
  __bf16* Ko  = Qo  + 4194304;
  __bf16* VTo = Ko  + 4194304;
  __bf16* Go  = VTo + 4194304;
  __bf16* At  = Go  + 4194304;

  hipFuncSetAttribute((const void*)proj_kernel, hipFuncAttributeMaxDynamicSharedMemorySize, 131072);

  hipMemsetAsync(flag, 0, sizeof(int), stream);
  cvt_all_kernel<<<2048, 256, 0, stream>>>(hs, qw, kw, vw, ow, Xb, qwb, kwb, vwb, owb,
                                           (const unsigned long long*)mask, flag);
  proj_kernel<<<256, 512, 131072, stream>>>(Xb, qwb, qb, kwb, kb, vwb, vb, Qo, Ko, VTo, Go);
  attn_kernel<<<512, 256, 0, stream>>>(Qo, Ko, VTo, Go, mask, flag, At);
  oproj_kernel<<<256, 256, 0, stream>>>(At, owb, ob, out);
}